// Round 6
// baseline (163.634 us; speedup 1.0000x reference)
//
#include <hip/hip_runtime.h>
#include <stdint.h>

typedef __attribute__((ext_vector_type(8))) short bf16x8;
typedef __attribute__((ext_vector_type(4))) float f32x4;
typedef __attribute__((ext_vector_type(4))) float float4v;
typedef __attribute__((ext_vector_type(8))) unsigned short u16x8;

#define DEV __device__ __forceinline__

DEV unsigned short f2bf(float f) {
    union { float f; uint32_t u; } v; v.f = f;
    uint32_t u = v.u;
    return (unsigned short)((u + 0x7FFFu + ((u >> 16) & 1u)) >> 16);
}

DEV unsigned int cvt_pk_bf16(float lo, float hi) {
    unsigned int r;
    asm("v_cvt_pk_bf16_f32 %0, %1, %2" : "=v"(r) : "v"(lo), "v"(hi));
    return r;
}

#if __has_builtin(__builtin_amdgcn_global_load_lds)
#define HAVE_GLDS 1
typedef const unsigned char __attribute__((address_space(1)))* as1p;
typedef unsigned char __attribute__((address_space(3)))* as3p;
DEV void gload16(const unsigned short* g, unsigned short* l) {
    __builtin_amdgcn_global_load_lds((as1p)(const void*)g, (as3p)(void*)l, 16, 0, 0);
}
#else
#define HAVE_GLDS 0
#endif

// ---------------------------------------------------------------------------
// 1) fp32 -> bf16 convert (x)
// ---------------------------------------------------------------------------
__global__ void k_cvt_x(const float* __restrict__ x, unsigned short* __restrict__ xb, int n4) {
    int i = blockIdx.x * blockDim.x + threadIdx.x;
    if (i >= n4) return;
    float4v v = *(const float4v*)(x + (size_t)i * 4);
    union { unsigned short s[4]; uint64_t q; } o;
    o.s[0] = f2bf(v[0]); o.s[1] = f2bf(v[1]); o.s[2] = f2bf(v[2]); o.s[3] = f2bf(v[3]);
    *(uint64_t*)(xb + (size_t)i * 4) = o.q;
}

// ---------------------------------------------------------------------------
// 2) fp32 [R][C] -> bf16 [C][R] convert + transpose
// ---------------------------------------------------------------------------
__global__ void k_cvt_tr_w(const float* __restrict__ w, unsigned short* __restrict__ wt,
                           int R, int C) {
    __shared__ alignas(16) unsigned short tile[64][65];
    const int t = threadIdx.x;
    const int tr = blockIdx.y * 64, tc = blockIdx.x * 64;
#pragma unroll
    for (int p = 0; p < 4; ++p) {
        int r = p * 16 + (t >> 4);
        int c = (t & 15) * 4;
        float4v v = *(const float4v*)(w + (size_t)(tr + r) * C + tc + c);
#pragma unroll
        for (int j = 0; j < 4; ++j) tile[r][c + j] = f2bf(v[j]);
    }
    __syncthreads();
#pragma unroll
    for (int p = 0; p < 2; ++p) {
        int r2 = p * 32 + (t >> 3);
        int k0 = (t & 7) * 8;
        u16x8 o;
#pragma unroll
        for (int j = 0; j < 8; ++j) o[j] = tile[k0 + j][r2];
        *(u16x8*)(wt + (size_t)(tc + r2) * R + tr + k0) = o;
    }
}

// ---------------------------------------------------------------------------
// 3) bf16 GEMM: C[M,N] = A[M,K] * Bt[N,K]^T.  128x128 tile, BK=64, 4 waves.
//    Staging via global_load_lds(16B) with pre-swizzled global source; LDS
//    reads keep the XOR swizzle (same involution both sides -> correct + no
//    read conflicts).  Falls back to reg-staging if builtin unavailable.
// ---------------------------------------------------------------------------
template <int OUT_BF16>
__global__ __launch_bounds__(256)
void k_gemm_bt(const unsigned short* __restrict__ A,
               const unsigned short* __restrict__ Bt,
               void* __restrict__ Cp, const float* __restrict__ bias,
               int M, int N, int K) {
    __shared__ alignas(16) unsigned short lA[128 * 64];
    __shared__ alignas(16) unsigned short lB[128 * 64];
    const int t = threadIdx.x;
    const int w = t >> 6, l = t & 63;
    const int l15 = l & 15, l4 = l >> 4;
    const int wm = (w >> 1) * 64, wn = (w & 1) * 64;
    const size_t bm = (size_t)blockIdx.y * 128, bn = (size_t)blockIdx.x * 128;

    int offA[4][2], offB[4][2];
#pragma unroll
    for (int f = 0; f < 4; ++f) {
        const int ra = wm + f * 16 + l15;
        const int rb = wn + f * 16 + l15;
#pragma unroll
        for (int kc = 0; kc < 2; ++kc) {
            offA[f][kc] = ra * 64 + (((kc * 4 + l4) ^ (ra & 7)) << 3);
            offB[f][kc] = rb * 64 + (((kc * 4 + l4) ^ (rb & 7)) << 3);
        }
    }

#if HAVE_GLDS
    // wave w stages rows [w*32, w*32+32) of A and B; 4 calls each (8 rows/call)
    const int srow8 = l >> 3;                 // row within 8-row group
    const int scol  = (l & 7) ^ srow8;        // pre-swizzled source col slot
    const unsigned short* gA = A  + (bm + w * 32 + srow8) * (size_t)K + scol * 8;
    const unsigned short* gB = Bt + (bn + w * 32 + srow8) * (size_t)K + scol * 8;
    unsigned short* dA = lA + (w * 32) * 64;
    unsigned short* dB = lB + (w * 32) * 64;
#else
    const int srow = t >> 3, sslot = t & 7;
    const int swoff = srow * 64 + ((sslot ^ (srow & 7)) << 3);
    const unsigned short* pA = A + (bm + srow) * (size_t)K + sslot * 8;
    const unsigned short* pB = Bt + (bn + srow) * (size_t)K + sslot * 8;
#endif

    const f32x4 zf = {0.f, 0.f, 0.f, 0.f};
    f32x4 acc[4][4];
#pragma unroll
    for (int i = 0; i < 4; ++i)
#pragma unroll
        for (int j = 0; j < 4; ++j) acc[i][j] = zf;

    for (int kt = 0; kt < K; kt += 64) {
#if HAVE_GLDS
        __syncthreads();   // previous tile fully consumed
#pragma unroll
        for (int i = 0; i < 4; ++i) {
            gload16(gA + (size_t)i * 8 * K + kt, dA + i * 8 * 64);
            gload16(gB + (size_t)i * 8 * K + kt, dB + i * 8 * 64);
        }
        __syncthreads();   // compiler drains vmcnt before barrier -> data ready
#else
        bf16x8 ra[4], rb[4];
#pragma unroll
        for (int p = 0; p < 4; ++p) {
            ra[p] = *(const bf16x8*)(pA + (size_t)p * 32 * K + kt);
            rb[p] = *(const bf16x8*)(pB + (size_t)p * 32 * K + kt);
        }
        __syncthreads();
#pragma unroll
        for (int p = 0; p < 4; ++p) {
            *(bf16x8*)(lA + p * 32 * 64 + swoff) = ra[p];
            *(bf16x8*)(lB + p * 32 * 64 + swoff) = rb[p];
        }
        __syncthreads();
#endif
#pragma unroll
        for (int kc = 0; kc < 2; ++kc) {
            bf16x8 af[4], bfr[4];
#pragma unroll
            for (int f = 0; f < 4; ++f) af[f] = *(const bf16x8*)(lA + offA[f][kc]);
#pragma unroll
            for (int f = 0; f < 4; ++f) bfr[f] = *(const bf16x8*)(lB + offB[f][kc]);
#pragma unroll
            for (int mf = 0; mf < 4; ++mf)
#pragma unroll
                for (int nf = 0; nf < 4; ++nf)
                    acc[mf][nf] = __builtin_amdgcn_mfma_f32_16x16x32_bf16(
                        af[mf], bfr[nf], acc[mf][nf], 0, 0, 0);
        }
    }

    if (OUT_BF16) {
        unsigned short* C = (unsigned short*)Cp;
#pragma unroll
        for (int mf = 0; mf < 4; ++mf)
#pragma unroll
            for (int nf = 0; nf < 4; ++nf) {
                const size_t row = bm + wm + mf * 16 + l4 * 4;
                const size_t col = bn + wn + nf * 16 + l15;
#pragma unroll
                for (int j = 0; j < 4; ++j)
                    C[(row + j) * (size_t)N + col] = f2bf(acc[mf][nf][j]);
            }
    } else {
        float* C = (float*)Cp;
#pragma unroll
        for (int nf = 0; nf < 4; ++nf) {
            const size_t col = bn + wn + nf * 16 + l15;
            const float bv = bias[col];
#pragma unroll
            for (int mf = 0; mf < 4; ++mf) {
                const size_t row = bm + wm + mf * 16 + l4 * 4;
#pragma unroll
                for (int j = 0; j < 4; ++j)
                    C[(row + j) * (size_t)N + col] = acc[mf][nf][j] + bv;
            }
        }
    }
}

// ---------------------------------------------------------------------------
// 4) V transpose: qkv v-cols -> vt[bh][d][n]
// ---------------------------------------------------------------------------
__global__ void k_tr_v(const unsigned short* __restrict__ qkv, unsigned short* __restrict__ vt) {
    __shared__ alignas(16) unsigned short tile[64][72];
    const int t = threadIdx.x;
    const int bh = blockIdx.y, b = bh >> 4, h = bh & 15;
    const int nb = blockIdx.x * 64;
#pragma unroll
    for (int p = 0; p < 2; ++p) {
        const int n = p * 32 + (t >> 3), d0 = (t & 7) * 8;
        u16x8 v = *(const u16x8*)(qkv + (size_t)(b * 2048 + nb + n) * 3072 + 2048 + h * 64 + d0);
#pragma unroll
        for (int j = 0; j < 8; ++j) tile[d0 + j][n] = v[j];
    }
    __syncthreads();
#pragma unroll
    for (int p = 0; p < 2; ++p) {
        const int d = p * 32 + (t >> 3), n0 = (t & 7) * 8;
        u16x8 v = *(const u16x8*)(&tile[d][n0]);
        *(u16x8*)(vt + (size_t)(bh * 64 + d) * 2048 + nb + n0) = v;
    }
}

// ---------------------------------------------------------------------------
// 5) Flash attention, swapped-QK, verified opcodes (16x16x32 MFMA only).
//    Round-6 deltas vs validated round-5 kernel:
//      - single-buffer K/V LDS (24KB total: lK 8 + lV 8 + lP 8) + KV-split
//        via blockIdx.z -> 2048 blocks, ~6 blocks/CU co-resident.
//      - rowsum via ones-column x32 MFMA (verified layout): accl rows align
//        with o rows -> no rowsum adds, no shfl in loop tail or epilogue.
//      - PARTIAL=1: write unnormalized O (f32) + m + l partials; combiner
//        merges the two KV halves exactly (flash-merge in fp32).
// ---------------------------------------------------------------------------
template <int PARTIAL>
__global__ __launch_bounds__(256)
void k_attn(const unsigned short* __restrict__ qkv, const unsigned short* __restrict__ vt,
            unsigned short* __restrict__ attn_out,
            float* __restrict__ po, float* __restrict__ pm, float* __restrict__ pl,
            int kvlen) {
    __shared__ alignas(16) unsigned short lK[64 * 64];
    __shared__ alignas(16) unsigned short lV[64 * 64];
    __shared__ alignas(16) unsigned short lP[4][16 * 64];
    const int t = threadIdx.x, w = t >> 6, l = t & 63;
    const int l15 = l & 15, l4 = l >> 4;
    const int bh = blockIdx.y, b = bh >> 4, h = bh & 15;
    const int qb = blockIdx.x * 64;
    const int kv0 = blockIdx.z * kvlen;
    const float QSCALE = 0.18033688011112042f;   // 0.125 * log2(e)

    const unsigned short* qptr =
        qkv + (size_t)(b * 2048 + qb + w * 16 + l15) * 3072 + h * 64 + l4 * 8;
    const bf16x8 aq0 = *(const bf16x8*)(qptr);
    const bf16x8 aq1 = *(const bf16x8*)(qptr + 32);

    const int srow = t >> 3, sslot = t & 7;
    const int swoff = srow * 64 + ((sslot ^ (srow & 7)) << 3);
    const unsigned short* kptr =
        qkv + (size_t)(b * 2048 + kv0 + srow) * 3072 + 1024 + h * 64 + sslot * 8;
    const unsigned short* vptr = vt + (size_t)(bh * 64 + srow) * 2048 + kv0 + sslot * 8;

    int offK[4][2];
#pragma unroll
    for (int nf = 0; nf < 4; ++nf) {
        const int r = nf * 16 + l15;
#pragma unroll
        for (int kc = 0; kc < 2; ++kc)
            offK[nf][kc] = r * 64 + (((kc * 4 + l4) ^ (r & 7)) << 3);
    }
    int offPw[4];
#pragma unroll
    for (int nf = 0; nf < 4; ++nf) {
        const int c = nf * 16 + l4 * 4;
        offPw[nf] = l15 * 64 + (((c >> 3) ^ (l15 & 7)) << 3) + (c & 7);
    }

    const f32x4 zf = {0.f, 0.f, 0.f, 0.f};
    f32x4 o[4];
#pragma unroll
    for (int df = 0; df < 4; ++df) o[df] = zf;
    f32x4 accl = zf;               // rowsum accumulator, rows aligned with o
    float m_run = -1e30f;
    unsigned short* Pw = &lP[w][0];
    const bf16x8 ones8 = {(short)0x3F80, (short)0x3F80, (short)0x3F80, (short)0x3F80,
                          (short)0x3F80, (short)0x3F80, (short)0x3F80, (short)0x3F80};

    // prologue: stage tile 0
    {
        bf16x8 rk[2], rv[2];
#pragma unroll
        for (int p = 0; p < 2; ++p) {
            rk[p] = *(const bf16x8*)(kptr + (size_t)(p * 32) * 3072);
            rv[p] = *(const bf16x8*)(vptr + (size_t)(p * 32) * 2048);
        }
#pragma unroll
        for (int p = 0; p < 2; ++p) {
            *(bf16x8*)(lK + p * 32 * 64 + swoff) = rk[p];
            *(bf16x8*)(lV + p * 32 * 64 + swoff) = rv[p];
        }
        __syncthreads();
    }

    for (int kt = 0; kt < kvlen; kt += 64) {
        const bool more = (kt + 64) < kvlen;
        // issue next tile's global loads early (hidden under compute)
        bf16x8 rk[2], rv[2];
        if (more) {
#pragma unroll
            for (int p = 0; p < 2; ++p) {
                rk[p] = *(const bf16x8*)(kptr + (size_t)(kt + 64 + p * 32) * 3072);
                rv[p] = *(const bf16x8*)(vptr + (size_t)(p * 32) * 2048 + kt + 64);
            }
        }

        // S^T = K Q^T : lane holds S_raw[kv = nf*16 + l4*4 + j][q = l15]
        f32x4 s[4];
#pragma unroll
        for (int nf = 0; nf < 4; ++nf) {
            const bf16x8 kf0 = *(const bf16x8*)(lK + offK[nf][0]);
            const bf16x8 kf1 = *(const bf16x8*)(lK + offK[nf][1]);
            f32x4 a = zf;
            a = __builtin_amdgcn_mfma_f32_16x16x32_bf16(kf0, aq0, a, 0, 0, 0);
            a = __builtin_amdgcn_mfma_f32_16x16x32_bf16(kf1, aq1, a, 0, 0, 0);
            s[nf] = a;
        }

        // row max over 16 lane-local values + 2 shfl across the 4 dup lanes
        float mx = fmaxf(fmaxf(s[0][0], s[0][1]), s[0][2]);
        mx = fmaxf(fmaxf(mx, s[0][3]), s[1][0]);
        mx = fmaxf(fmaxf(mx, s[1][1]), s[1][2]);
        mx = fmaxf(fmaxf(mx, s[1][3]), s[2][0]);
        mx = fmaxf(fmaxf(mx, s[2][1]), s[2][2]);
        mx = fmaxf(fmaxf(mx, s[2][3]), s[3][0]);
        mx = fmaxf(fmaxf(mx, s[3][1]), s[3][2]);
        mx = fmaxf(mx, s[3][3]);
        mx = fmaxf(mx, __shfl_xor(mx, 16));
        mx = fmaxf(mx, __shfl_xor(mx, 32));
        mx *= QSCALE;   // into scaled log2 domain

        // defer-max: rescale only when the row max grew by > 8 (log2 domain)
        if (!__all(mx <= m_run + 8.0f)) {
            const float mn = fmaxf(m_run, mx);
            const float alpha = exp2f(m_run - mn);
            m_run = mn;
            const float a0 = __shfl(alpha, l4 * 4 + 0);
            const float a1 = __shfl(alpha, l4 * 4 + 1);
            const float a2 = __shfl(alpha, l4 * 4 + 2);
            const float a3 = __shfl(alpha, l4 * 4 + 3);
#pragma unroll
            for (int df = 0; df < 4; ++df) {
                o[df][0] *= a0; o[df][1] *= a1; o[df][2] *= a2; o[df][3] *= a3;
            }
            accl[0] *= a0; accl[1] *= a1; accl[2] *= a2; accl[3] *= a3;
        }

        // P = exp2(QSCALE*s_raw - m), packed to per-wave LDS (b64 writes)
#pragma unroll
        for (int nf = 0; nf < 4; ++nf) {
            const float p0 = exp2f(fmaf(s[nf][0], QSCALE, -m_run));
            const float p1 = exp2f(fmaf(s[nf][1], QSCALE, -m_run));
            const float p2 = exp2f(fmaf(s[nf][2], QSCALE, -m_run));
            const float p3 = exp2f(fmaf(s[nf][3], QSCALE, -m_run));
            union { unsigned int d[2]; uint64_t q; } u;
            u.d[0] = cvt_pk_bf16(p0, p1);
            u.d[1] = cvt_pk_bf16(p2, p3);
            *(uint64_t*)(Pw + offPw[nf]) = u.q;
        }

        // O += P V ; rowsum via ones-column on the MFMA pipe (accl rows = o rows)
        const bf16x8 ap0 = *(const bf16x8*)(Pw + l15 * 64 + ((l4 ^ (l15 & 7)) << 3));
        const bf16x8 ap1 = *(const bf16x8*)(Pw + l15 * 64 + (((4 + l4) ^ (l15 & 7)) << 3));
        accl = __builtin_amdgcn_mfma_f32_16x16x32_bf16(ap0, ones8, accl, 0, 0, 0);
        accl = __builtin_amdgcn_mfma_f32_16x16x32_bf16(ap1, ones8, accl, 0, 0, 0);
#pragma unroll
        for (int df = 0; df < 4; ++df) {
            const int r = df * 16 + l15;
            const bf16x8 bv0 = *(const bf16x8*)(lV + r * 64 + ((l4 ^ (r & 7)) << 3));
            const bf16x8 bv1 = *(const bf16x8*)(lV + r * 64 + (((4 + l4) ^ (r & 7)) << 3));
            o[df] = __builtin_amdgcn_mfma_f32_16x16x32_bf16(ap0, bv0, o[df], 0, 0, 0);
            o[df] = __builtin_amdgcn_mfma_f32_16x16x32_bf16(ap1, bv1, o[df], 0, 0, 0);
        }

        // single-buffer: all reads done -> barrier -> write next tile -> barrier
        if (more) {
            __syncthreads();
#pragma unroll
            for (int p = 0; p < 2; ++p) {
                *(bf16x8*)(lK + p * 32 * 64 + swoff) = rk[p];
                *(bf16x8*)(lV + p * 32 * 64 + swoff) = rv[p];
            }
            __syncthreads();
        }
    }

    const int rowb = b * 2048 + qb + w * 16 + l4 * 4;
    if (PARTIAL) {
        const size_t zoff = (size_t)blockIdx.z * 4096;
#pragma unroll
        for (int df = 0; df < 4; ++df) {
            const int d = df * 16 + l15;
#pragma unroll
            for (int j = 0; j < 4; ++j)
                po[(zoff + rowb + j) * 1024 + h * 64 + d] = o[df][j];
        }
        if (l15 == 0) {
#pragma unroll
            for (int j = 0; j < 4; ++j)
                pl[(zoff + rowb + j) * 16 + h] = accl[j];
        }
        if (l4 == 0)
            pm[(zoff + (b * 2048 + qb + w * 16 + l15)) * 16 + h] = m_run;
    } else {
        const float r0 = 1.0f / accl[0];
        const float r1 = 1.0f / accl[1];
        const float r2 = 1.0f / accl[2];
        const float r3 = 1.0f / accl[3];
#pragma unroll
        for (int df = 0; df < 4; ++df) {
            const int d = df * 16 + l15;
            attn_out[(size_t)(rowb + 0) * 1024 + h * 64 + d] = f2bf(o[df][0] * r0);
            attn_out[(size_t)(rowb + 1) * 1024 + h * 64 + d] = f2bf(o[df][1] * r1);
            attn_out[(size_t)(rowb + 2) * 1024 + h * 64 + d] = f2bf(o[df][2] * r2);
            attn_out[(size_t)(rowb + 3) * 1024 + h * 64 + d] = f2bf(o[df][3] * r3);
        }
    }
}

// ---------------------------------------------------------------------------
// 6) Combine the 2 KV-split halves: O = (O0*w0 + O1*w1) / (l0*w0 + l1*w1)
// ---------------------------------------------------------------------------
__global__ __launch_bounds__(256)
void k_combine(const float* __restrict__ po, const float* __restrict__ pm,
               const float* __restrict__ pl, unsigned short* __restrict__ attn) {
    const int r = blockIdx.x;
    const int t = threadIdx.x;
    const int hh = t >> 4, d0 = (t & 15) * 4;
    const float m0 = pm[(size_t)r * 16 + hh];
    const float m1 = pm[((size_t)4096 + r) * 16 + hh];
    const float m = fmaxf(m0, m1);
    const float w0 = exp2f(m0 - m), w1 = exp2f(m1 - m);
    const float lsum = pl[(size_t)r * 16 + hh] * w0 + pl[((size_t)4096 + r) * 16 + hh] * w1;
    const float4v o0 = *(const float4v*)(po + (size_t)r * 1024 + hh * 64 + d0);
    const float4v o1 = *(const float4v*)(po + ((size_t)4096 + r) * 1024 + hh * 64 + d0);
    const float inv = 1.0f / lsum;
    union { unsigned short s[4]; uint64_t q; } u;
#pragma unroll
    for (int j = 0; j < 4; ++j) u.s[j] = f2bf((o0[j] * w0 + o1[j] * w1) * inv);
    *(uint64_t*)(attn + (size_t)r * 1024 + hh * 64 + d0) = u.q;
}

// ---------------------------------------------------------------------------
extern "C" void kernel_launch(void* const* d_in, const int* in_sizes, int n_in,
                              void* d_out, int out_size, void* d_ws, size_t ws_size,
                              hipStream_t stream) {
    const float* x      = (const float*)d_in[0];
    const float* w_qkv  = (const float*)d_in[1];
    const float* w_proj = (const float*)d_in[2];
    const float* b_proj = (const float*)d_in[3];
    float* out = (float*)d_out;

    char* ws = (char*)d_ws;
    // split-2 layout needs 75 MB (po aliases xb/wqkvT, which die after QKV GEMM)
    const size_t NEED2 = 78643200;
    const bool split2 = ws_size >= NEED2;

    unsigned short *xb, *wqkvT, *wprojT, *qkv, *vt, *attn;
    float *po = nullptr, *pm = nullptr, *pl = nullptr;
    if (split2) {
        qkv    = (unsigned short*)(ws + 0);           // 24M
        vt     = (unsigned short*)(ws + 25165824);    //  8M
        attn   = (unsigned short*)(ws + 33554432);    //  8M
        wprojT = (unsigned short*)(ws + 41943040);    //  2M
        pm     = (float*)(ws + 44040192);             // 512K
        pl     = (float*)(ws + 44564480);             // 512K
        po     = (float*)(ws + 45088768);             // 32M  (aliases xb+wqkvT)
        xb     = (unsigned short*)(ws + 45088768);    //  8M  (dead before po written)
        wqkvT  = (unsigned short*)(ws + 53477376);    //  6M  (dead before po written)
    } else {
        xb     = (unsigned short*)(ws + 0);           //  8M
        wqkvT  = (unsigned short*)(ws + 8388608);     //  6M
        wprojT = (unsigned short*)(ws + 14680064);    //  2M
        qkv    = (unsigned short*)(ws + 16777216);    // 24M
        vt     = (unsigned short*)(ws + 41943040);    //  8M
        attn   = (unsigned short*)(ws + 50331648);    //  8M
    }

    k_cvt_x<<<dim3(4096), dim3(256), 0, stream>>>(x, xb, 4096 * 1024 / 4);
    k_cvt_tr_w<<<dim3(48, 16), dim3(256), 0, stream>>>(w_qkv, wqkvT, 1024, 3072);
    k_cvt_tr_w<<<dim3(16, 16), dim3(256), 0, stream>>>(w_proj, wprojT, 1024, 1024);
    k_gemm_bt<1><<<dim3(24, 32), dim3(256), 0, stream>>>(xb, wqkvT, (void*)qkv, (const float*)nullptr, 4096, 3072, 1024);
    k_tr_v<<<dim3(32, 32), dim3(256), 0, stream>>>(qkv, vt);
    if (split2) {
        k_attn<1><<<dim3(32, 32, 2), dim3(256), 0, stream>>>(qkv, vt, attn, po, pm, pl, 1024);
        k_combine<<<dim3(4096), dim3(256), 0, stream>>>(po, pm, pl, attn);
    } else {
        k_attn<0><<<dim3(32, 32, 1), dim3(256), 0, stream>>>(qkv, vt, attn, po, pm, pl, 2048);
    }
    k_gemm_bt<0><<<dim3(8, 32), dim3(256), 0, stream>>>(attn, wprojT, (void*)out, b_proj, 4096, 1024, 1024);
}

// Round 7
// 141.062 us; speedup vs baseline: 1.1600x; 1.1600x over previous
//
#include <hip/hip_runtime.h>
#include <stdint.h>

typedef __attribute__((ext_vector_type(8))) short bf16x8;
typedef __attribute__((ext_vector_type(4))) float f32x4;
typedef __attribute__((ext_vector_type(4))) float float4v;
typedef __attribute__((ext_vector_type(8))) unsigned short u16x8;

#define DEV __device__ __forceinline__

DEV unsigned short f2bf(float f) {
    union { float f; uint32_t u; } v; v.f = f;
    uint32_t u = v.u;
    return (unsigned short)((u + 0x7FFFu + ((u >> 16) & 1u)) >> 16);
}

DEV unsigned int cvt_pk_bf16(float lo, float hi) {
    unsigned int r;
    asm("v_cvt_pk_bf16_f32 %0, %1, %2" : "=v"(r) : "v"(lo), "v"(hi));
    return r;
}

#if __has_builtin(__builtin_amdgcn_global_load_lds)
#define HAVE_GLDS 1
typedef const unsigned char __attribute__((address_space(1)))* as1p;
typedef unsigned char __attribute__((address_space(3)))* as3p;
DEV void gload16(const unsigned short* g, unsigned short* l) {
    __builtin_amdgcn_global_load_lds((as1p)(const void*)g, (as3p)(void*)l, 16, 0, 0);
}
#else
#define HAVE_GLDS 0
#endif

// ---------------------------------------------------------------------------
// 1) fp32 -> bf16 convert (x)
// ---------------------------------------------------------------------------
__global__ void k_cvt_x(const float* __restrict__ x, unsigned short* __restrict__ xb, int n4) {
    int i = blockIdx.x * blockDim.x + threadIdx.x;
    if (i >= n4) return;
    float4v v = *(const float4v*)(x + (size_t)i * 4);
    union { unsigned short s[4]; uint64_t q; } o;
    o.s[0] = f2bf(v[0]); o.s[1] = f2bf(v[1]); o.s[2] = f2bf(v[2]); o.s[3] = f2bf(v[3]);
    *(uint64_t*)(xb + (size_t)i * 4) = o.q;
}

// ---------------------------------------------------------------------------
// 2) fp32 [R][C] -> bf16 [C][R] convert + transpose
// ---------------------------------------------------------------------------
__global__ void k_cvt_tr_w(const float* __restrict__ w, unsigned short* __restrict__ wt,
                           int R, int C) {
    __shared__ alignas(16) unsigned short tile[64][65];
    const int t = threadIdx.x;
    const int tr = blockIdx.y * 64, tc = blockIdx.x * 64;
#pragma unroll
    for (int p = 0; p < 4; ++p) {
        int r = p * 16 + (t >> 4);
        int c = (t & 15) * 4;
        float4v v = *(const float4v*)(w + (size_t)(tr + r) * C + tc + c);
#pragma unroll
        for (int j = 0; j < 4; ++j) tile[r][c + j] = f2bf(v[j]);
    }
    __syncthreads();
#pragma unroll
    for (int p = 0; p < 2; ++p) {
        int r2 = p * 32 + (t >> 3);
        int k0 = (t & 7) * 8;
        u16x8 o;
#pragma unroll
        for (int j = 0; j < 8; ++j) o[j] = tile[k0 + j][r2];
        *(u16x8*)(wt + (size_t)(tc + r2) * R + tr + k0) = o;
    }
}

// ---------------------------------------------------------------------------
// 3) bf16 GEMM: C[M,N] = A[M,K] * Bt[N,K]^T.  128x128 tile, BK=64, 4 waves.
//    global_load_lds(16B) staging with pre-swizzled global source (both-sides
//    involution); reg-staging fallback.
// ---------------------------------------------------------------------------
template <int OUT_BF16>
__global__ __launch_bounds__(256)
void k_gemm_bt(const unsigned short* __restrict__ A,
               const unsigned short* __restrict__ Bt,
               void* __restrict__ Cp, const float* __restrict__ bias,
               int M, int N, int K) {
    __shared__ alignas(16) unsigned short lA[128 * 64];
    __shared__ alignas(16) unsigned short lB[128 * 64];
    const int t = threadIdx.x;
    const int w = t >> 6, l = t & 63;
    const int l15 = l & 15, l4 = l >> 4;
    const int wm = (w >> 1) * 64, wn = (w & 1) * 64;
    const size_t bm = (size_t)blockIdx.y * 128, bn = (size_t)blockIdx.x * 128;

    int offA[4][2], offB[4][2];
#pragma unroll
    for (int f = 0; f < 4; ++f) {
        const int ra = wm + f * 16 + l15;
        const int rb = wn + f * 16 + l15;
#pragma unroll
        for (int kc = 0; kc < 2; ++kc) {
            offA[f][kc] = ra * 64 + (((kc * 4 + l4) ^ (ra & 7)) << 3);
            offB[f][kc] = rb * 64 + (((kc * 4 + l4) ^ (rb & 7)) << 3);
        }
    }

#if HAVE_GLDS
    const int srow8 = l >> 3;
    const int scol  = (l & 7) ^ srow8;
    const unsigned short* gA = A  + (bm + w * 32 + srow8) * (size_t)K + scol * 8;
    const unsigned short* gB = Bt + (bn + w * 32 + srow8) * (size_t)K + scol * 8;
    unsigned short* dA = lA + (w * 32) * 64;
    unsigned short* dB = lB + (w * 32) * 64;
#else
    const int srow = t >> 3, sslot = t & 7;
    const int swoff = srow * 64 + ((sslot ^ (srow & 7)) << 3);
    const unsigned short* pA = A + (bm + srow) * (size_t)K + sslot * 8;
    const unsigned short* pB = Bt + (bn + srow) * (size_t)K + sslot * 8;
#endif

    const f32x4 zf = {0.f, 0.f, 0.f, 0.f};
    f32x4 acc[4][4];
#pragma unroll
    for (int i = 0; i < 4; ++i)
#pragma unroll
        for (int j = 0; j < 4; ++j) acc[i][j] = zf;

    for (int kt = 0; kt < K; kt += 64) {
#if HAVE_GLDS
        __syncthreads();
#pragma unroll
        for (int i = 0; i < 4; ++i) {
            gload16(gA + (size_t)i * 8 * K + kt, dA + i * 8 * 64);
            gload16(gB + (size_t)i * 8 * K + kt, dB + i * 8 * 64);
        }
        __syncthreads();
#else
        bf16x8 ra[4], rb[4];
#pragma unroll
        for (int p = 0; p < 4; ++p) {
            ra[p] = *(const bf16x8*)(pA + (size_t)p * 32 * K + kt);
            rb[p] = *(const bf16x8*)(pB + (size_t)p * 32 * K + kt);
        }
        __syncthreads();
#pragma unroll
        for (int p = 0; p < 4; ++p) {
            *(bf16x8*)(lA + p * 32 * 64 + swoff) = ra[p];
            *(bf16x8*)(lB + p * 32 * 64 + swoff) = rb[p];
        }
        __syncthreads();
#endif
#pragma unroll
        for (int kc = 0; kc < 2; ++kc) {
            bf16x8 af[4], bfr[4];
#pragma unroll
            for (int f = 0; f < 4; ++f) af[f] = *(const bf16x8*)(lA + offA[f][kc]);
#pragma unroll
            for (int f = 0; f < 4; ++f) bfr[f] = *(const bf16x8*)(lB + offB[f][kc]);
#pragma unroll
            for (int mf = 0; mf < 4; ++mf)
#pragma unroll
                for (int nf = 0; nf < 4; ++nf)
                    acc[mf][nf] = __builtin_amdgcn_mfma_f32_16x16x32_bf16(
                        af[mf], bfr[nf], acc[mf][nf], 0, 0, 0);
        }
    }

    if (OUT_BF16) {
        unsigned short* C = (unsigned short*)Cp;
#pragma unroll
        for (int mf = 0; mf < 4; ++mf)
#pragma unroll
            for (int nf = 0; nf < 4; ++nf) {
                const size_t row = bm + wm + mf * 16 + l4 * 4;
                const size_t col = bn + wn + nf * 16 + l15;
#pragma unroll
                for (int j = 0; j < 4; ++j)
                    C[(row + j) * (size_t)N + col] = f2bf(acc[mf][nf][j]);
            }
    } else {
        float* C = (float*)Cp;
#pragma unroll
        for (int nf = 0; nf < 4; ++nf) {
            const size_t col = bn + wn + nf * 16 + l15;
            const float bv = bias[col];
#pragma unroll
            for (int mf = 0; mf < 4; ++mf) {
                const size_t row = bm + wm + mf * 16 + l4 * 4;
#pragma unroll
                for (int j = 0; j < 4; ++j)
                    C[(row + j) * (size_t)N + col] = acc[mf][nf][j] + bv;
            }
        }
    }
}

// ---------------------------------------------------------------------------
// 4) V transpose: qkv v-cols -> vt[bh][d][n]
// ---------------------------------------------------------------------------
__global__ void k_tr_v(const unsigned short* __restrict__ qkv, unsigned short* __restrict__ vt) {
    __shared__ alignas(16) unsigned short tile[64][72];
    const int t = threadIdx.x;
    const int bh = blockIdx.y, b = bh >> 4, h = bh & 15;
    const int nb = blockIdx.x * 64;
#pragma unroll
    for (int p = 0; p < 2; ++p) {
        const int n = p * 32 + (t >> 3), d0 = (t & 7) * 8;
        u16x8 v = *(const u16x8*)(qkv + (size_t)(b * 2048 + nb + n) * 3072 + 2048 + h * 64 + d0);
#pragma unroll
        for (int j = 0; j < 8; ++j) tile[d0 + j][n] = v[j];
    }
    __syncthreads();
#pragma unroll
    for (int p = 0; p < 2; ++p) {
        const int d = p * 32 + (t >> 3), n0 = (t & 7) * 8;
        u16x8 v = *(const u16x8*)(&tile[d][n0]);
        *(u16x8*)(vt + (size_t)(bh * 64 + d) * 2048 + nb + n0) = v;
    }
}

// ---------------------------------------------------------------------------
// 5) Flash attention, swapped-QK, verified opcodes (16x16x32 MFMA only).
//    R7 = R5 shell (dbuf 40KB -> exactly 4 blocks/CU, 1024 blocks, 1
//    barrier/iter, defer-max) + R6-validated ones-MFMA rowsum (accl rows
//    align with o rows: no rowsum adds, no epilogue shuffles) + T5 setprio
//    around the MFMA clusters.
// ---------------------------------------------------------------------------
__global__ __launch_bounds__(256, 4)
void k_attn(const unsigned short* __restrict__ qkv, const unsigned short* __restrict__ vt,
            unsigned short* __restrict__ attn_out) {
    __shared__ alignas(16) unsigned short lK[2][64 * 64];
    __shared__ alignas(16) unsigned short lV[2][64 * 64];
    __shared__ alignas(16) unsigned short lP[4][16 * 64];
    const int t = threadIdx.x, w = t >> 6, l = t & 63;
    const int l15 = l & 15, l4 = l >> 4;
    const int bh = blockIdx.y, b = bh >> 4, h = bh & 15;
    const int qb = blockIdx.x * 64;
    const float QSCALE = 0.18033688011112042f;   // 0.125 * log2(e)

    const unsigned short* qptr =
        qkv + (size_t)(b * 2048 + qb + w * 16 + l15) * 3072 + h * 64 + l4 * 8;
    const bf16x8 aq0 = *(const bf16x8*)(qptr);
    const bf16x8 aq1 = *(const bf16x8*)(qptr + 32);

    const int srow = t >> 3, sslot = t & 7;
    const int swoff = srow * 64 + ((sslot ^ (srow & 7)) << 3);
    const unsigned short* kptr = qkv + (size_t)(b * 2048 + srow) * 3072 + 1024 + h * 64 + sslot * 8;
    const unsigned short* vptr = vt + (size_t)(bh * 64 + srow) * 2048 + sslot * 8;

    int offK[4][2];
#pragma unroll
    for (int nf = 0; nf < 4; ++nf) {
        const int r = nf * 16 + l15;
#pragma unroll
        for (int kc = 0; kc < 2; ++kc)
            offK[nf][kc] = r * 64 + (((kc * 4 + l4) ^ (r & 7)) << 3);
    }
    int offPw[4];
#pragma unroll
    for (int nf = 0; nf < 4; ++nf) {
        const int c = nf * 16 + l4 * 4;
        offPw[nf] = l15 * 64 + (((c >> 3) ^ (l15 & 7)) << 3) + (c & 7);
    }

    const f32x4 zf = {0.f, 0.f, 0.f, 0.f};
    f32x4 o[4];
#pragma unroll
    for (int df = 0; df < 4; ++df) o[df] = zf;
    f32x4 accl = zf;               // rowsum accumulator, rows aligned with o
    float m_run = -1e30f;
    unsigned short* Pw = &lP[w][0];
    const bf16x8 ones8 = {(short)0x3F80, (short)0x3F80, (short)0x3F80, (short)0x3F80,
                          (short)0x3F80, (short)0x3F80, (short)0x3F80, (short)0x3F80};

    // prologue: stage tile 0 into buffer 0
    {
        bf16x8 rk[2], rv[2];
#pragma unroll
        for (int p = 0; p < 2; ++p) {
            rk[p] = *(const bf16x8*)(kptr + (size_t)(p * 32) * 3072);
            rv[p] = *(const bf16x8*)(vptr + (size_t)(p * 32) * 2048);
        }
#pragma unroll
        for (int p = 0; p < 2; ++p) {
            *(bf16x8*)(&lK[0][0] + p * 32 * 64 + swoff) = rk[p];
            *(bf16x8*)(&lV[0][0] + p * 32 * 64 + swoff) = rv[p];
        }
        __syncthreads();
    }

#pragma unroll 2
    for (int kt = 0; kt < 2048; kt += 64) {
        const int cur = (kt >> 6) & 1;
        const unsigned short* K = &lK[cur][0];
        const unsigned short* V = &lV[cur][0];

        // issue next tile's global loads early (hidden under compute)
        bf16x8 rk[2], rv[2];
        const bool more = (kt + 64) < 2048;
        if (more) {
#pragma unroll
            for (int p = 0; p < 2; ++p) {
                rk[p] = *(const bf16x8*)(kptr + (size_t)(kt + 64 + p * 32) * 3072);
                rv[p] = *(const bf16x8*)(vptr + (size_t)(p * 32) * 2048 + kt + 64);
            }
        }

        // S^T = K Q^T : lane holds S_raw[kv = nf*16 + l4*4 + j][q = l15]
        f32x4 s[4];
        __builtin_amdgcn_s_setprio(1);
#pragma unroll
        for (int nf = 0; nf < 4; ++nf) {
            const bf16x8 kf0 = *(const bf16x8*)(K + offK[nf][0]);
            const bf16x8 kf1 = *(const bf16x8*)(K + offK[nf][1]);
            f32x4 a = zf;
            a = __builtin_amdgcn_mfma_f32_16x16x32_bf16(kf0, aq0, a, 0, 0, 0);
            a = __builtin_amdgcn_mfma_f32_16x16x32_bf16(kf1, aq1, a, 0, 0, 0);
            s[nf] = a;
        }
        __builtin_amdgcn_s_setprio(0);

        // row max over 16 lane-local values + 2 shfl across the 4 dup lanes
        float mx = fmaxf(fmaxf(s[0][0], s[0][1]), s[0][2]);
        mx = fmaxf(fmaxf(mx, s[0][3]), s[1][0]);
        mx = fmaxf(fmaxf(mx, s[1][1]), s[1][2]);
        mx = fmaxf(fmaxf(mx, s[1][3]), s[2][0]);
        mx = fmaxf(fmaxf(mx, s[2][1]), s[2][2]);
        mx = fmaxf(fmaxf(mx, s[2][3]), s[3][0]);
        mx = fmaxf(fmaxf(mx, s[3][1]), s[3][2]);
        mx = fmaxf(mx, s[3][3]);
        mx = fmaxf(mx, __shfl_xor(mx, 16));
        mx = fmaxf(mx, __shfl_xor(mx, 32));
        mx *= QSCALE;   // into scaled log2 domain

        // defer-max: rescale only when the row max grew by > 8 (log2 domain)
        if (!__all(mx <= m_run + 8.0f)) {
            const float mn = fmaxf(m_run, mx);
            const float alpha = exp2f(m_run - mn);
            m_run = mn;
            const float a0 = __shfl(alpha, l4 * 4 + 0);
            const float a1 = __shfl(alpha, l4 * 4 + 1);
            const float a2 = __shfl(alpha, l4 * 4 + 2);
            const float a3 = __shfl(alpha, l4 * 4 + 3);
#pragma unroll
            for (int df = 0; df < 4; ++df) {
                o[df][0] *= a0; o[df][1] *= a1; o[df][2] *= a2; o[df][3] *= a3;
            }
            accl[0] *= a0; accl[1] *= a1; accl[2] *= a2; accl[3] *= a3;
        }

        // P = exp2(QSCALE*s_raw - m), packed to per-wave LDS (b64 writes)
#pragma unroll
        for (int nf = 0; nf < 4; ++nf) {
            const float p0 = exp2f(fmaf(s[nf][0], QSCALE, -m_run));
            const float p1 = exp2f(fmaf(s[nf][1], QSCALE, -m_run));
            const float p2 = exp2f(fmaf(s[nf][2], QSCALE, -m_run));
            const float p3 = exp2f(fmaf(s[nf][3], QSCALE, -m_run));
            union { unsigned int d[2]; uint64_t q; } u;
            u.d[0] = cvt_pk_bf16(p0, p1);
            u.d[1] = cvt_pk_bf16(p2, p3);
            *(uint64_t*)(Pw + offPw[nf]) = u.q;
        }

        // O += P V ; rowsum via ones-column on the MFMA pipe
        const bf16x8 ap0 = *(const bf16x8*)(Pw + l15 * 64 + ((l4 ^ (l15 & 7)) << 3));
        const bf16x8 ap1 = *(const bf16x8*)(Pw + l15 * 64 + (((4 + l4) ^ (l15 & 7)) << 3));
        __builtin_amdgcn_s_setprio(1);
        accl = __builtin_amdgcn_mfma_f32_16x16x32_bf16(ap0, ones8, accl, 0, 0, 0);
        accl = __builtin_amdgcn_mfma_f32_16x16x32_bf16(ap1, ones8, accl, 0, 0, 0);
#pragma unroll
        for (int df = 0; df < 4; ++df) {
            const int r = df * 16 + l15;
            const bf16x8 bv0 = *(const bf16x8*)(V + r * 64 + ((l4 ^ (r & 7)) << 3));
            const bf16x8 bv1 = *(const bf16x8*)(V + r * 64 + (((4 + l4) ^ (r & 7)) << 3));
            o[df] = __builtin_amdgcn_mfma_f32_16x16x32_bf16(ap0, bv0, o[df], 0, 0, 0);
            o[df] = __builtin_amdgcn_mfma_f32_16x16x32_bf16(ap1, bv1, o[df], 0, 0, 0);
        }
        __builtin_amdgcn_s_setprio(0);

        // write next tile into the other buffer; single barrier per iter
        if (more) {
#pragma unroll
            for (int p = 0; p < 2; ++p) {
                *(bf16x8*)(&lK[cur ^ 1][0] + p * 32 * 64 + swoff) = rk[p];
                *(bf16x8*)(&lV[cur ^ 1][0] + p * 32 * 64 + swoff) = rv[p];
            }
        }
        __syncthreads();
    }

    // epilogue: O / l  (accl rows aligned with o rows -> no shuffles)
    const float r0 = 1.0f / accl[0];
    const float r1 = 1.0f / accl[1];
    const float r2 = 1.0f / accl[2];
    const float r3 = 1.0f / accl[3];
    const int rowb = b * 2048 + qb + w * 16 + l4 * 4;
#pragma unroll
    for (int df = 0; df < 4; ++df) {
        const int d = df * 16 + l15;
        attn_out[(size_t)(rowb + 0) * 1024 + h * 64 + d] = f2bf(o[df][0] * r0);
        attn_out[(size_t)(rowb + 1) * 1024 + h * 64 + d] = f2bf(o[df][1] * r1);
        attn_out[(size_t)(rowb + 2) * 1024 + h * 64 + d] = f2bf(o[df][2] * r2);
        attn_out[(size_t)(rowb + 3) * 1024 + h * 64 + d] = f2bf(o[df][3] * r3);
    }
}

// ---------------------------------------------------------------------------
extern "C" void kernel_launch(void* const* d_in, const int* in_sizes, int n_in,
                              void* d_out, int out_size, void* d_ws, size_t ws_size,
                              hipStream_t stream) {
    const float* x      = (const float*)d_in[0];
    const float* w_qkv  = (const float*)d_in[1];
    const float* w_proj = (const float*)d_in[2];
    const float* b_proj = (const float*)d_in[3];
    float* out = (float*)d_out;

    char* ws = (char*)d_ws;
    unsigned short* xb     = (unsigned short*)(ws + 0);           //  8M
    unsigned short* wqkvT  = (unsigned short*)(ws + 8388608);     //  6M
    unsigned short* wprojT = (unsigned short*)(ws + 14680064);    //  2M
    unsigned short* qkv    = (unsigned short*)(ws + 16777216);    // 24M
    unsigned short* vt     = (unsigned short*)(ws + 41943040);    //  8M
    unsigned short* attn   = (unsigned short*)(ws + 50331648);    //  8M

    k_cvt_x<<<dim3(4096), dim3(256), 0, stream>>>(x, xb, 4096 * 1024 / 4);
    k_cvt_tr_w<<<dim3(48, 16), dim3(256), 0, stream>>>(w_qkv, wqkvT, 1024, 3072);
    k_cvt_tr_w<<<dim3(16, 16), dim3(256), 0, stream>>>(w_proj, wprojT, 1024, 1024);
    k_gemm_bt<1><<<dim3(24, 32), dim3(256), 0, stream>>>(xb, wqkvT, (void*)qkv, (const float*)nullptr, 4096, 3072, 1024);
    k_tr_v<<<dim3(32, 32), dim3(256), 0, stream>>>(qkv, vt);
    k_attn<<<dim3(32, 32), dim3(256), 0, stream>>>(qkv, vt, attn);
    k_gemm_bt<0><<<dim3(8, 32), dim3(256), 0, stream>>>(attn, wprojT, (void*)out, b_proj, 4096, 1024, 1024);
}

// Round 8
// 139.069 us; speedup vs baseline: 1.1766x; 1.0143x over previous
//
#include <hip/hip_runtime.h>
#include <stdint.h>

typedef __attribute__((ext_vector_type(8))) short bf16x8;
typedef __attribute__((ext_vector_type(4))) float f32x4;
typedef __attribute__((ext_vector_type(4))) float float4v;
typedef __attribute__((ext_vector_type(8))) unsigned short u16x8;

#define DEV __device__ __forceinline__

DEV unsigned short f2bf(float f) {
    union { float f; uint32_t u; } v; v.f = f;
    uint32_t u = v.u;
    return (unsigned short)((u + 0x7FFFu + ((u >> 16) & 1u)) >> 16);
}

DEV unsigned int cvt_pk_bf16(float lo, float hi) {
    unsigned int r;
    asm("v_cvt_pk_bf16_f32 %0, %1, %2" : "=v"(r) : "v"(lo), "v"(hi));
    return r;
}

#if __has_builtin(__builtin_amdgcn_global_load_lds)
#define HAVE_GLDS 1
typedef const unsigned char __attribute__((address_space(1)))* as1p;
typedef unsigned char __attribute__((address_space(3)))* as3p;
DEV void gload16(const unsigned short* g, unsigned short* l) {
    __builtin_amdgcn_global_load_lds((as1p)(const void*)g, (as3p)(void*)l, 16, 0, 0);
}
#else
#define HAVE_GLDS 0
#endif

// ---------------------------------------------------------------------------
// 1) fp32 -> bf16 convert (x)
// ---------------------------------------------------------------------------
__global__ void k_cvt_x(const float* __restrict__ x, unsigned short* __restrict__ xb, int n4) {
    int i = blockIdx.x * blockDim.x + threadIdx.x;
    if (i >= n4) return;
    float4v v = *(const float4v*)(x + (size_t)i * 4);
    union { unsigned short s[4]; uint64_t q; } o;
    o.s[0] = f2bf(v[0]); o.s[1] = f2bf(v[1]); o.s[2] = f2bf(v[2]); o.s[3] = f2bf(v[3]);
    *(uint64_t*)(xb + (size_t)i * 4) = o.q;
}

// ---------------------------------------------------------------------------
// 2) fp32 [R][C] -> bf16 [C][R] convert + transpose
// ---------------------------------------------------------------------------
__global__ void k_cvt_tr_w(const float* __restrict__ w, unsigned short* __restrict__ wt,
                           int R, int C) {
    __shared__ alignas(16) unsigned short tile[64][65];
    const int t = threadIdx.x;
    const int tr = blockIdx.y * 64, tc = blockIdx.x * 64;
#pragma unroll
    for (int p = 0; p < 4; ++p) {
        int r = p * 16 + (t >> 4);
        int c = (t & 15) * 4;
        float4v v = *(const float4v*)(w + (size_t)(tr + r) * C + tc + c);
#pragma unroll
        for (int j = 0; j < 4; ++j) tile[r][c + j] = f2bf(v[j]);
    }
    __syncthreads();
#pragma unroll
    for (int p = 0; p < 2; ++p) {
        int r2 = p * 32 + (t >> 3);
        int k0 = (t & 7) * 8;
        u16x8 o;
#pragma unroll
        for (int j = 0; j < 8; ++j) o[j] = tile[k0 + j][r2];
        *(u16x8*)(wt + (size_t)(tc + r2) * R + tr + k0) = o;
    }
}

// ---------------------------------------------------------------------------
// 3) bf16 GEMM: C[M,N] = A[M,K] * Bt[N,K]^T.  128x128 tile, BK=64, 4 waves.
//    global_load_lds(16B) staging with pre-swizzled global source.
//    OUT_BF16=1 + vt_out: column tiles with bn>=2048 (the V third of the QKV
//    output) are written TRANSPOSED into vt[bh][d][n] (packed u64 of 4
//    consecutive n) and skipped in qkv -- fuses the old k_tr_v kernel away.
// ---------------------------------------------------------------------------
template <int OUT_BF16>
__global__ __launch_bounds__(256)
void k_gemm_bt(const unsigned short* __restrict__ A,
               const unsigned short* __restrict__ Bt,
               void* __restrict__ Cp, const float* __restrict__ bias,
               unsigned short* __restrict__ vt_out,
               int M, int N, int K) {
    __shared__ alignas(16) unsigned short lA[128 * 64];
    __shared__ alignas(16) unsigned short lB[128 * 64];
    const int t = threadIdx.x;
    const int w = t >> 6, l = t & 63;
    const int l15 = l & 15, l4 = l >> 4;
    const int wm = (w >> 1) * 64, wn = (w & 1) * 64;
    const size_t bm = (size_t)blockIdx.y * 128, bn = (size_t)blockIdx.x * 128;

    int offA[4][2], offB[4][2];
#pragma unroll
    for (int f = 0; f < 4; ++f) {
        const int ra = wm + f * 16 + l15;
        const int rb = wn + f * 16 + l15;
#pragma unroll
        for (int kc = 0; kc < 2; ++kc) {
            offA[f][kc] = ra * 64 + (((kc * 4 + l4) ^ (ra & 7)) << 3);
            offB[f][kc] = rb * 64 + (((kc * 4 + l4) ^ (rb & 7)) << 3);
        }
    }

#if HAVE_GLDS
    const int srow8 = l >> 3;
    const int scol  = (l & 7) ^ srow8;
    const unsigned short* gA = A  + (bm + w * 32 + srow8) * (size_t)K + scol * 8;
    const unsigned short* gB = Bt + (bn + w * 32 + srow8) * (size_t)K + scol * 8;
    unsigned short* dA = lA + (w * 32) * 64;
    unsigned short* dB = lB + (w * 32) * 64;
#else
    const int srow = t >> 3, sslot = t & 7;
    const int swoff = srow * 64 + ((sslot ^ (srow & 7)) << 3);
    const unsigned short* pA = A + (bm + srow) * (size_t)K + sslot * 8;
    const unsigned short* pB = Bt + (bn + srow) * (size_t)K + sslot * 8;
#endif

    const f32x4 zf = {0.f, 0.f, 0.f, 0.f};
    f32x4 acc[4][4];
#pragma unroll
    for (int i = 0; i < 4; ++i)
#pragma unroll
        for (int j = 0; j < 4; ++j) acc[i][j] = zf;

    for (int kt = 0; kt < K; kt += 64) {
#if HAVE_GLDS
        __syncthreads();
#pragma unroll
        for (int i = 0; i < 4; ++i) {
            gload16(gA + (size_t)i * 8 * K + kt, dA + i * 8 * 64);
            gload16(gB + (size_t)i * 8 * K + kt, dB + i * 8 * 64);
        }
        __syncthreads();
#else
        bf16x8 ra[4], rb[4];
#pragma unroll
        for (int p = 0; p < 4; ++p) {
            ra[p] = *(const bf16x8*)(pA + (size_t)p * 32 * K + kt);
            rb[p] = *(const bf16x8*)(pB + (size_t)p * 32 * K + kt);
        }
        __syncthreads();
#pragma unroll
        for (int p = 0; p < 4; ++p) {
            *(bf16x8*)(lA + p * 32 * 64 + swoff) = ra[p];
            *(bf16x8*)(lB + p * 32 * 64 + swoff) = rb[p];
        }
        __syncthreads();
#endif
#pragma unroll
        for (int kc = 0; kc < 2; ++kc) {
            bf16x8 af[4], bfr[4];
#pragma unroll
            for (int f = 0; f < 4; ++f) af[f] = *(const bf16x8*)(lA + offA[f][kc]);
#pragma unroll
            for (int f = 0; f < 4; ++f) bfr[f] = *(const bf16x8*)(lB + offB[f][kc]);
#pragma unroll
            for (int mf = 0; mf < 4; ++mf)
#pragma unroll
                for (int nf = 0; nf < 4; ++nf)
                    acc[mf][nf] = __builtin_amdgcn_mfma_f32_16x16x32_bf16(
                        af[mf], bfr[nf], acc[mf][nf], 0, 0, 0);
        }
    }

    if (OUT_BF16) {
        if (vt_out && bn >= 2048) {
            // V region: write transposed into vt[bh*64+dd][n] (n = seq pos)
            const int bb = (int)(bm >> 11);              // batch index
            const int n0 = (int)(bm & 2047) + wm + l4 * 4;
#pragma unroll
            for (int nf = 0; nf < 4; ++nf) {
                const int d = (int)(bn - 2048) + wn + nf * 16 + l15;
                unsigned short* vrow = vt_out + ((size_t)(bb * 16 + (d >> 6)) * 64 + (d & 63)) * 2048;
#pragma unroll
                for (int mf = 0; mf < 4; ++mf) {
                    union { unsigned short s[4]; uint64_t q; } u;
#pragma unroll
                    for (int j = 0; j < 4; ++j) u.s[j] = f2bf(acc[mf][nf][j]);
                    *(uint64_t*)(vrow + n0 + mf * 16) = u.q;
                }
            }
        } else {
            unsigned short* C = (unsigned short*)Cp;
#pragma unroll
            for (int mf = 0; mf < 4; ++mf)
#pragma unroll
                for (int nf = 0; nf < 4; ++nf) {
                    const size_t row = bm + wm + mf * 16 + l4 * 4;
                    const size_t col = bn + wn + nf * 16 + l15;
#pragma unroll
                    for (int j = 0; j < 4; ++j)
                        C[(row + j) * (size_t)N + col] = f2bf(acc[mf][nf][j]);
                }
        }
    } else {
        float* C = (float*)Cp;
#pragma unroll
        for (int nf = 0; nf < 4; ++nf) {
            const size_t col = bn + wn + nf * 16 + l15;
            const float bv = bias[col];
#pragma unroll
            for (int mf = 0; mf < 4; ++mf) {
                const size_t row = bm + wm + mf * 16 + l4 * 4;
#pragma unroll
                for (int j = 0; j < 4; ++j)
                    C[(row + j) * (size_t)N + col] = acc[mf][nf][j] + bv;
            }
        }
    }
}

// ---------------------------------------------------------------------------
// 5) Flash attention, swapped-QK, verified opcodes (16x16x32 MFMA only).
//    R8 delta vs R7: K/V staging via global_load_lds(16B) with pre-swizzled
//    source (linear LDS dest == our swizzled layout; rule-21 both-sides).
//    Removes the reg round-trip + 4 ds_write_b128/iter. Everything else
//    (dbuf 40KB = 4 blocks/CU, 1 barrier/iter, defer-max, MFMA rowsum,
//    setprio) identical to the validated R7 kernel.
// ---------------------------------------------------------------------------
__global__ __launch_bounds__(256, 4)
void k_attn(const unsigned short* __restrict__ qkv, const unsigned short* __restrict__ vt,
            unsigned short* __restrict__ attn_out) {
    __shared__ alignas(16) unsigned short lK[2][64 * 64];
    __shared__ alignas(16) unsigned short lV[2][64 * 64];
    __shared__ alignas(16) unsigned short lP[4][16 * 64];
    const int t = threadIdx.x, w = t >> 6, l = t & 63;
    const int l15 = l & 15, l4 = l >> 4;
    const int bh = blockIdx.y, b = bh >> 4, h = bh & 15;
    const int qb = blockIdx.x * 64;
    const float QSCALE = 0.18033688011112042f;   // 0.125 * log2(e)

    const unsigned short* qptr =
        qkv + (size_t)(b * 2048 + qb + w * 16 + l15) * 3072 + h * 64 + l4 * 8;
    const bf16x8 aq0 = *(const bf16x8*)(qptr);
    const bf16x8 aq1 = *(const bf16x8*)(qptr + 32);

#if HAVE_GLDS
    // wave w stages K rows and V rows w*16 .. w*16+15 (2 calls x 8 rows each)
    const int gr = l >> 3;                 // row within 8-row group
    const int gs = (l & 7) ^ gr;           // pre-swizzled source col slot
    const unsigned short* gK = qkv + (size_t)(b * 2048 + w * 16 + gr) * 3072 + 1024 + h * 64 + gs * 8;
    const unsigned short* gV = vt + (size_t)(bh * 64 + w * 16 + gr) * 2048 + gs * 8;
#else
    const int srow = t >> 3, sslot = t & 7;
    const int swoff = srow * 64 + ((sslot ^ (srow & 7)) << 3);
    const unsigned short* kptr = qkv + (size_t)(b * 2048 + srow) * 3072 + 1024 + h * 64 + sslot * 8;
    const unsigned short* vptr = vt + (size_t)(bh * 64 + srow) * 2048 + sslot * 8;
#endif

    int offK[4][2];
#pragma unroll
    for (int nf = 0; nf < 4; ++nf) {
        const int r = nf * 16 + l15;
#pragma unroll
        for (int kc = 0; kc < 2; ++kc)
            offK[nf][kc] = r * 64 + (((kc * 4 + l4) ^ (r & 7)) << 3);
    }
    int offPw[4];
#pragma unroll
    for (int nf = 0; nf < 4; ++nf) {
        const int c = nf * 16 + l4 * 4;
        offPw[nf] = l15 * 64 + (((c >> 3) ^ (l15 & 7)) << 3) + (c & 7);
    }

    const f32x4 zf = {0.f, 0.f, 0.f, 0.f};
    f32x4 o[4];
#pragma unroll
    for (int df = 0; df < 4; ++df) o[df] = zf;
    f32x4 accl = zf;               // rowsum accumulator, rows aligned with o
    float m_run = -1e30f;
    unsigned short* Pw = &lP[w][0];
    const bf16x8 ones8 = {(short)0x3F80, (short)0x3F80, (short)0x3F80, (short)0x3F80,
                          (short)0x3F80, (short)0x3F80, (short)0x3F80, (short)0x3F80};

    // prologue: stage tile 0 into buffer 0
#if HAVE_GLDS
#pragma unroll
    for (int i = 0; i < 2; ++i) {
        gload16(gK + (size_t)i * 8 * 3072, &lK[0][(w * 16 + i * 8) * 64]);
        gload16(gV + (size_t)i * 8 * 2048, &lV[0][(w * 16 + i * 8) * 64]);
    }
    __syncthreads();
#else
    {
        bf16x8 rk[2], rv[2];
#pragma unroll
        for (int p = 0; p < 2; ++p) {
            rk[p] = *(const bf16x8*)(kptr + (size_t)(p * 32) * 3072);
            rv[p] = *(const bf16x8*)(vptr + (size_t)(p * 32) * 2048);
        }
#pragma unroll
        for (int p = 0; p < 2; ++p) {
            *(bf16x8*)(&lK[0][0] + p * 32 * 64 + swoff) = rk[p];
            *(bf16x8*)(&lV[0][0] + p * 32 * 64 + swoff) = rv[p];
        }
        __syncthreads();
    }
#endif

#pragma unroll 2
    for (int kt = 0; kt < 2048; kt += 64) {
        const int cur = (kt >> 6) & 1;
        const unsigned short* K = &lK[cur][0];
        const unsigned short* V = &lV[cur][0];
        const bool more = (kt + 64) < 2048;

        // issue next tile's staging early (async, drained at end-of-iter barrier)
#if HAVE_GLDS
        if (more) {
#pragma unroll
            for (int i = 0; i < 2; ++i) {
                gload16(gK + (size_t)(kt + 64 + i * 8) * 3072, &lK[cur ^ 1][(w * 16 + i * 8) * 64]);
                gload16(gV + (size_t)i * 8 * 2048 + kt + 64,   &lV[cur ^ 1][(w * 16 + i * 8) * 64]);
            }
        }
#else
        bf16x8 rk[2], rv[2];
        if (more) {
#pragma unroll
            for (int p = 0; p < 2; ++p) {
                rk[p] = *(const bf16x8*)(kptr + (size_t)(kt + 64 + p * 32) * 3072);
                rv[p] = *(const bf16x8*)(vptr + (size_t)(p * 32) * 2048 + kt + 64);
            }
        }
#endif

        // S^T = K Q^T : lane holds S_raw[kv = nf*16 + l4*4 + j][q = l15]
        f32x4 s[4];
        __builtin_amdgcn_s_setprio(1);
#pragma unroll
        for (int nf = 0; nf < 4; ++nf) {
            const bf16x8 kf0 = *(const bf16x8*)(K + offK[nf][0]);
            const bf16x8 kf1 = *(const bf16x8*)(K + offK[nf][1]);
            f32x4 a = zf;
            a = __builtin_amdgcn_mfma_f32_16x16x32_bf16(kf0, aq0, a, 0, 0, 0);
            a = __builtin_amdgcn_mfma_f32_16x16x32_bf16(kf1, aq1, a, 0, 0, 0);
            s[nf] = a;
        }
        __builtin_amdgcn_s_setprio(0);

        // row max over 16 lane-local values + 2 shfl across the 4 dup lanes
        float mx = fmaxf(fmaxf(s[0][0], s[0][1]), s[0][2]);
        mx = fmaxf(fmaxf(mx, s[0][3]), s[1][0]);
        mx = fmaxf(fmaxf(mx, s[1][1]), s[1][2]);
        mx = fmaxf(fmaxf(mx, s[1][3]), s[2][0]);
        mx = fmaxf(fmaxf(mx, s[2][1]), s[2][2]);
        mx = fmaxf(fmaxf(mx, s[2][3]), s[3][0]);
        mx = fmaxf(fmaxf(mx, s[3][1]), s[3][2]);
        mx = fmaxf(mx, s[3][3]);
        mx = fmaxf(mx, __shfl_xor(mx, 16));
        mx = fmaxf(mx, __shfl_xor(mx, 32));
        mx *= QSCALE;   // into scaled log2 domain

        // defer-max: rescale only when the row max grew by > 8 (log2 domain)
        if (!__all(mx <= m_run + 8.0f)) {
            const float mn = fmaxf(m_run, mx);
            const float alpha = exp2f(m_run - mn);
            m_run = mn;
            const float a0 = __shfl(alpha, l4 * 4 + 0);
            const float a1 = __shfl(alpha, l4 * 4 + 1);
            const float a2 = __shfl(alpha, l4 * 4 + 2);
            const float a3 = __shfl(alpha, l4 * 4 + 3);
#pragma unroll
            for (int df = 0; df < 4; ++df) {
                o[df][0] *= a0; o[df][1] *= a1; o[df][2] *= a2; o[df][3] *= a3;
            }
            accl[0] *= a0; accl[1] *= a1; accl[2] *= a2; accl[3] *= a3;
        }

        // P = exp2(QSCALE*s_raw - m), packed to per-wave LDS (b64 writes)
#pragma unroll
        for (int nf = 0; nf < 4; ++nf) {
            const float p0 = exp2f(fmaf(s[nf][0], QSCALE, -m_run));
            const float p1 = exp2f(fmaf(s[nf][1], QSCALE, -m_run));
            const float p2 = exp2f(fmaf(s[nf][2], QSCALE, -m_run));
            const float p3 = exp2f(fmaf(s[nf][3], QSCALE, -m_run));
            union { unsigned int d[2]; uint64_t q; } u;
            u.d[0] = cvt_pk_bf16(p0, p1);
            u.d[1] = cvt_pk_bf16(p2, p3);
            *(uint64_t*)(Pw + offPw[nf]) = u.q;
        }

        // O += P V ; rowsum via ones-column on the MFMA pipe
        const bf16x8 ap0 = *(const bf16x8*)(Pw + l15 * 64 + ((l4 ^ (l15 & 7)) << 3));
        const bf16x8 ap1 = *(const bf16x8*)(Pw + l15 * 64 + (((4 + l4) ^ (l15 & 7)) << 3));
        __builtin_amdgcn_s_setprio(1);
        accl = __builtin_amdgcn_mfma_f32_16x16x32_bf16(ap0, ones8, accl, 0, 0, 0);
        accl = __builtin_amdgcn_mfma_f32_16x16x32_bf16(ap1, ones8, accl, 0, 0, 0);
#pragma unroll
        for (int df = 0; df < 4; ++df) {
            const int r = df * 16 + l15;
            const bf16x8 bv0 = *(const bf16x8*)(V + r * 64 + ((l4 ^ (r & 7)) << 3));
            const bf16x8 bv1 = *(const bf16x8*)(V + r * 64 + (((4 + l4) ^ (r & 7)) << 3));
            o[df] = __builtin_amdgcn_mfma_f32_16x16x32_bf16(ap0, bv0, o[df], 0, 0, 0);
            o[df] = __builtin_amdgcn_mfma_f32_16x16x32_bf16(ap1, bv1, o[df], 0, 0, 0);
        }
        __builtin_amdgcn_s_setprio(0);

#if !HAVE_GLDS
        if (more) {
#pragma unroll
            for (int p = 0; p < 2; ++p) {
                *(bf16x8*)(&lK[cur ^ 1][0] + p * 32 * 64 + swoff) = rk[p];
                *(bf16x8*)(&lV[cur ^ 1][0] + p * 32 * 64 + swoff) = rv[p];
            }
        }
#endif
        __syncthreads();
    }

    // epilogue: O / l  (accl rows aligned with o rows -> no shuffles)
    const float r0 = 1.0f / accl[0];
    const float r1 = 1.0f / accl[1];
    const float r2 = 1.0f / accl[2];
    const float r3 = 1.0f / accl[3];
    const int rowb = b * 2048 + qb + w * 16 + l4 * 4;
#pragma unroll
    for (int df = 0; df < 4; ++df) {
        const int d = df * 16 + l15;
        attn_out[(size_t)(rowb + 0) * 1024 + h * 64 + d] = f2bf(o[df][0] * r0);
        attn_out[(size_t)(rowb + 1) * 1024 + h * 64 + d] = f2bf(o[df][1] * r1);
        attn_out[(size_t)(rowb + 2) * 1024 + h * 64 + d] = f2bf(o[df][2] * r2);
        attn_out[(size_t)(rowb + 3) * 1024 + h * 64 + d] = f2bf(o[df][3] * r3);
    }
}

// ---------------------------------------------------------------------------
extern "C" void kernel_launch(void* const* d_in, const int* in_sizes, int n_in,
                              void* d_out, int out_size, void* d_ws, size_t ws_size,
                              hipStream_t stream) {
    const float* x      = (const float*)d_in[0];
    const float* w_qkv  = (const float*)d_in[1];
    const float* w_proj = (const float*)d_in[2];
    const float* b_proj = (const float*)d_in[3];
    float* out = (float*)d_out;

    char* ws = (char*)d_ws;
    unsigned short* xb     = (unsigned short*)(ws + 0);           //  8M
    unsigned short* wqkvT  = (unsigned short*)(ws + 8388608);     //  6M
    unsigned short* wprojT = (unsigned short*)(ws + 14680064);    //  2M
    unsigned short* qkv    = (unsigned short*)(ws + 16777216);    // 24M
    unsigned short* vt     = (unsigned short*)(ws + 41943040);    //  8M
    unsigned short* attn   = (unsigned short*)(ws + 50331648);    //  8M

    k_cvt_x<<<dim3(4096), dim3(256), 0, stream>>>(x, xb, 4096 * 1024 / 4);
    k_cvt_tr_w<<<dim3(48, 16), dim3(256), 0, stream>>>(w_qkv, wqkvT, 1024, 3072);
    k_cvt_tr_w<<<dim3(16, 16), dim3(256), 0, stream>>>(w_proj, wprojT, 1024, 1024);
    k_gemm_bt<1><<<dim3(24, 32), dim3(256), 0, stream>>>(xb, wqkvT, (void*)qkv, (const float*)nullptr, vt, 4096, 3072, 1024);
    k_attn<<<dim3(32, 32), dim3(256), 0, stream>>>(qkv, vt, attn);
    k_gemm_bt<0><<<dim3(8, 32), dim3(256), 0, stream>>>(attn, wprojT, (void*)out, b_proj, (unsigned short*)nullptr, 4096, 1024, 1024);
}

// Round 9
// 133.228 us; speedup vs baseline: 1.2282x; 1.0438x over previous
//
#include <hip/hip_runtime.h>
#include <stdint.h>

typedef __attribute__((ext_vector_type(8))) short bf16x8;
typedef __attribute__((ext_vector_type(4))) float f32x4;
typedef __attribute__((ext_vector_type(4))) float float4v;
typedef __attribute__((ext_vector_type(8))) unsigned short u16x8;

#define DEV __device__ __forceinline__

DEV unsigned short f2bf(float f) {
    union { float f; uint32_t u; } v; v.f = f;
    uint32_t u = v.u;
    return (unsigned short)((u + 0x7FFFu + ((u >> 16) & 1u)) >> 16);
}

DEV unsigned int cvt_pk_bf16(float lo, float hi) {
    unsigned int r;
    asm("v_cvt_pk_bf16_f32 %0, %1, %2" : "=v"(r) : "v"(lo), "v"(hi));
    return r;
}

#if __has_builtin(__builtin_amdgcn_global_load_lds)
#define HAVE_GLDS 1
typedef const unsigned char __attribute__((address_space(1)))* as1p;
typedef unsigned char __attribute__((address_space(3)))* as3p;
DEV void gload16(const unsigned short* g, unsigned short* l) {
    __builtin_amdgcn_global_load_lds((as1p)(const void*)g, (as3p)(void*)l, 16, 0, 0);
}
#else
#define HAVE_GLDS 0
#endif

// ---------------------------------------------------------------------------
// 1) fp32 -> bf16 convert (x)
// ---------------------------------------------------------------------------
__global__ void k_cvt_x(const float* __restrict__ x, unsigned short* __restrict__ xb, int n4) {
    int i = blockIdx.x * blockDim.x + threadIdx.x;
    if (i >= n4) return;
    float4v v = *(const float4v*)(x + (size_t)i * 4);
    union { unsigned short s[4]; uint64_t q; } o;
    o.s[0] = f2bf(v[0]); o.s[1] = f2bf(v[1]); o.s[2] = f2bf(v[2]); o.s[3] = f2bf(v[3]);
    *(uint64_t*)(xb + (size_t)i * 4) = o.q;
}

// ---------------------------------------------------------------------------
// 2) fp32 [R][C] -> bf16 [C][R] convert + transpose
// ---------------------------------------------------------------------------
__global__ void k_cvt_tr_w(const float* __restrict__ w, unsigned short* __restrict__ wt,
                           int R, int C) {
    __shared__ alignas(16) unsigned short tile[64][65];
    const int t = threadIdx.x;
    const int tr = blockIdx.y * 64, tc = blockIdx.x * 64;
#pragma unroll
    for (int p = 0; p < 4; ++p) {
        int r = p * 16 + (t >> 4);
        int c = (t & 15) * 4;
        float4v v = *(const float4v*)(w + (size_t)(tr + r) * C + tc + c);
#pragma unroll
        for (int j = 0; j < 4; ++j) tile[r][c + j] = f2bf(v[j]);
    }
    __syncthreads();
#pragma unroll
    for (int p = 0; p < 2; ++p) {
        int r2 = p * 32 + (t >> 3);
        int k0 = (t & 7) * 8;
        u16x8 o;
#pragma unroll
        for (int j = 0; j < 8; ++j) o[j] = tile[k0 + j][r2];
        *(u16x8*)(wt + (size_t)(tc + r2) * R + tr + k0) = o;
    }
}

// ---------------------------------------------------------------------------
// 3) bf16 GEMM: C[M,N] = A[M,K] * Bt[N,K]^T.  Tile 128M x BN, BK=64, 4 waves.
//    BN=128: waves 2x2 of 64x64 (4x4 frags).  BN=64: waves 2x2 of 64x32
//    (4x2 frags) -> 2x the blocks for small-N GEMMs (proj: 512 blocks, 2/CU).
//    global_load_lds(16B) staging with pre-swizzled global source.
//    OUT_BF16=1 + vt_out: V-third columns (bn>=2048) written transposed into
//    vt[bh][d][n] (fused k_tr_v).
// ---------------------------------------------------------------------------
template <int OUT_BF16, int BN>
__global__ __launch_bounds__(256)
void k_gemm_bt(const unsigned short* __restrict__ A,
               const unsigned short* __restrict__ Bt,
               void* __restrict__ Cp, const float* __restrict__ bias,
               unsigned short* __restrict__ vt_out,
               int M, int N, int K) {
    constexpr int NFR = BN / 32;          // N frags per wave
    __shared__ alignas(16) unsigned short lA[128 * 64];
    __shared__ alignas(16) unsigned short lB[BN * 64];
    const int t = threadIdx.x;
    const int w = t >> 6, l = t & 63;
    const int l15 = l & 15, l4 = l >> 4;
    const int wm = (w >> 1) * 64, wn = (w & 1) * (BN / 2);
    const size_t bm = (size_t)blockIdx.y * 128, bn = (size_t)blockIdx.x * BN;

    int offA[4][2], offB[NFR][2];
#pragma unroll
    for (int f = 0; f < 4; ++f) {
        const int ra = wm + f * 16 + l15;
#pragma unroll
        for (int kc = 0; kc < 2; ++kc)
            offA[f][kc] = ra * 64 + (((kc * 4 + l4) ^ (ra & 7)) << 3);
    }
#pragma unroll
    for (int f = 0; f < NFR; ++f) {
        const int rb = wn + f * 16 + l15;
#pragma unroll
        for (int kc = 0; kc < 2; ++kc)
            offB[f][kc] = rb * 64 + (((kc * 4 + l4) ^ (rb & 7)) << 3);
    }

#if HAVE_GLDS
    const int srow8 = l >> 3;
    const int scol  = (l & 7) ^ srow8;
    const unsigned short* gA = A  + (bm + w * 32 + srow8) * (size_t)K + scol * 8;
    const unsigned short* gB = Bt + (bn + w * (BN / 4) + srow8) * (size_t)K + scol * 8;
    unsigned short* dA = lA + (w * 32) * 64;
    unsigned short* dB = lB + (w * (BN / 4)) * 64;
#else
    const int srow = t >> 3, sslot = t & 7;
    const int swoff = srow * 64 + ((sslot ^ (srow & 7)) << 3);
    const unsigned short* pA = A + (bm + srow) * (size_t)K + sslot * 8;
    const unsigned short* pB = Bt + (bn + srow) * (size_t)K + sslot * 8;
#endif

    const f32x4 zf = {0.f, 0.f, 0.f, 0.f};
    f32x4 acc[4][NFR];
#pragma unroll
    for (int i = 0; i < 4; ++i)
#pragma unroll
        for (int j = 0; j < NFR; ++j) acc[i][j] = zf;

    for (int kt = 0; kt < K; kt += 64) {
#if HAVE_GLDS
        __syncthreads();
#pragma unroll
        for (int i = 0; i < 4; ++i)
            gload16(gA + (size_t)i * 8 * K + kt, dA + i * 8 * 64);
#pragma unroll
        for (int i = 0; i < BN / 32; ++i)
            gload16(gB + (size_t)i * 8 * K + kt, dB + i * 8 * 64);
        __syncthreads();
#else
        bf16x8 ra[4], rb[BN / 32];
#pragma unroll
        for (int p = 0; p < 4; ++p)
            ra[p] = *(const bf16x8*)(pA + (size_t)p * 32 * K + kt);
#pragma unroll
        for (int p = 0; p < BN / 32; ++p)
            rb[p] = *(const bf16x8*)(pB + (size_t)p * 32 * K + kt);
        __syncthreads();
#pragma unroll
        for (int p = 0; p < 4; ++p)
            *(bf16x8*)(lA + p * 32 * 64 + swoff) = ra[p];
#pragma unroll
        for (int p = 0; p < BN / 32; ++p)
            *(bf16x8*)(lB + p * 32 * 64 + swoff) = rb[p];
        __syncthreads();
#endif
#pragma unroll
        for (int kc = 0; kc < 2; ++kc) {
            bf16x8 af[4], bfr[NFR];
#pragma unroll
            for (int f = 0; f < 4; ++f) af[f] = *(const bf16x8*)(lA + offA[f][kc]);
#pragma unroll
            for (int f = 0; f < NFR; ++f) bfr[f] = *(const bf16x8*)(lB + offB[f][kc]);
#pragma unroll
            for (int mf = 0; mf < 4; ++mf)
#pragma unroll
                for (int nf = 0; nf < NFR; ++nf)
                    acc[mf][nf] = __builtin_amdgcn_mfma_f32_16x16x32_bf16(
                        af[mf], bfr[nf], acc[mf][nf], 0, 0, 0);
        }
    }

    if (OUT_BF16) {
        if (vt_out && bn >= 2048) {
            // V region: write transposed into vt[bh*64+dd][n] (n = seq pos)
            const int bb = (int)(bm >> 11);
            const int n0 = (int)(bm & 2047) + wm + l4 * 4;
#pragma unroll
            for (int nf = 0; nf < NFR; ++nf) {
                const int d = (int)(bn - 2048) + wn + nf * 16 + l15;
                unsigned short* vrow = vt_out + ((size_t)(bb * 16 + (d >> 6)) * 64 + (d & 63)) * 2048;
#pragma unroll
                for (int mf = 0; mf < 4; ++mf) {
                    union { unsigned short s[4]; uint64_t q; } u;
#pragma unroll
                    for (int j = 0; j < 4; ++j) u.s[j] = f2bf(acc[mf][nf][j]);
                    *(uint64_t*)(vrow + n0 + mf * 16) = u.q;
                }
            }
        } else {
            unsigned short* C = (unsigned short*)Cp;
#pragma unroll
            for (int mf = 0; mf < 4; ++mf)
#pragma unroll
                for (int nf = 0; nf < NFR; ++nf) {
                    const size_t row = bm + wm + mf * 16 + l4 * 4;
                    const size_t col = bn + wn + nf * 16 + l15;
#pragma unroll
                    for (int j = 0; j < 4; ++j)
                        C[(row + j) * (size_t)N + col] = f2bf(acc[mf][nf][j]);
                }
        }
    } else {
        float* C = (float*)Cp;
#pragma unroll
        for (int nf = 0; nf < NFR; ++nf) {
            const size_t col = bn + wn + nf * 16 + l15;
            const float bv = bias[col];
#pragma unroll
            for (int mf = 0; mf < 4; ++mf) {
                const size_t row = bm + wm + mf * 16 + l4 * 4;
#pragma unroll
                for (int j = 0; j < 4; ++j)
                    C[(row + j) * (size_t)N + col] = acc[mf][nf][j] + bv;
            }
        }
    }
}

// ---------------------------------------------------------------------------
// 5) Flash attention — R7-identical (reg-staged dbuf, 1 barrier/iter,
//    defer-max, MFMA ones-rowsum, setprio). R8's GLDS staging reverted:
//    it moved the staging wait to the barrier tail (-6% measured).
// ---------------------------------------------------------------------------
__global__ __launch_bounds__(256, 4)
void k_attn(const unsigned short* __restrict__ qkv, const unsigned short* __restrict__ vt,
            unsigned short* __restrict__ attn_out) {
    __shared__ alignas(16) unsigned short lK[2][64 * 64];
    __shared__ alignas(16) unsigned short lV[2][64 * 64];
    __shared__ alignas(16) unsigned short lP[4][16 * 64];
    const int t = threadIdx.x, w = t >> 6, l = t & 63;
    const int l15 = l & 15, l4 = l >> 4;
    const int bh = blockIdx.y, b = bh >> 4, h = bh & 15;
    const int qb = blockIdx.x * 64;
    const float QSCALE = 0.18033688011112042f;   // 0.125 * log2(e)

    const unsigned short* qptr =
        qkv + (size_t)(b * 2048 + qb + w * 16 + l15) * 3072 + h * 64 + l4 * 8;
    const bf16x8 aq0 = *(const bf16x8*)(qptr);
    const bf16x8 aq1 = *(const bf16x8*)(qptr + 32);

    const int srow = t >> 3, sslot = t & 7;
    const int swoff = srow * 64 + ((sslot ^ (srow & 7)) << 3);
    const unsigned short* kptr = qkv + (size_t)(b * 2048 + srow) * 3072 + 1024 + h * 64 + sslot * 8;
    const unsigned short* vptr = vt + (size_t)(bh * 64 + srow) * 2048 + sslot * 8;

    int offK[4][2];
#pragma unroll
    for (int nf = 0; nf < 4; ++nf) {
        const int r = nf * 16 + l15;
#pragma unroll
        for (int kc = 0; kc < 2; ++kc)
            offK[nf][kc] = r * 64 + (((kc * 4 + l4) ^ (r & 7)) << 3);
    }
    int offPw[4];
#pragma unroll
    for (int nf = 0; nf < 4; ++nf) {
        const int c = nf * 16 + l4 * 4;
        offPw[nf] = l15 * 64 + (((c >> 3) ^ (l15 & 7)) << 3) + (c & 7);
    }

    const f32x4 zf = {0.f, 0.f, 0.f, 0.f};
    f32x4 o[4];
#pragma unroll
    for (int df = 0; df < 4; ++df) o[df] = zf;
    f32x4 accl = zf;
    float m_run = -1e30f;
    unsigned short* Pw = &lP[w][0];
    const bf16x8 ones8 = {(short)0x3F80, (short)0x3F80, (short)0x3F80, (short)0x3F80,
                          (short)0x3F80, (short)0x3F80, (short)0x3F80, (short)0x3F80};

    // prologue: stage tile 0 into buffer 0
    {
        bf16x8 rk[2], rv[2];
#pragma unroll
        for (int p = 0; p < 2; ++p) {
            rk[p] = *(const bf16x8*)(kptr + (size_t)(p * 32) * 3072);
            rv[p] = *(const bf16x8*)(vptr + (size_t)(p * 32) * 2048);
        }
#pragma unroll
        for (int p = 0; p < 2; ++p) {
            *(bf16x8*)(&lK[0][0] + p * 32 * 64 + swoff) = rk[p];
            *(bf16x8*)(&lV[0][0] + p * 32 * 64 + swoff) = rv[p];
        }
        __syncthreads();
    }

#pragma unroll 2
    for (int kt = 0; kt < 2048; kt += 64) {
        const int cur = (kt >> 6) & 1;
        const unsigned short* K = &lK[cur][0];
        const unsigned short* V = &lV[cur][0];

        bf16x8 rk[2], rv[2];
        const bool more = (kt + 64) < 2048;
        if (more) {
#pragma unroll
            for (int p = 0; p < 2; ++p) {
                rk[p] = *(const bf16x8*)(kptr + (size_t)(kt + 64 + p * 32) * 3072);
                rv[p] = *(const bf16x8*)(vptr + (size_t)(p * 32) * 2048 + kt + 64);
            }
        }

        // S^T = K Q^T : lane holds S_raw[kv = nf*16 + l4*4 + j][q = l15]
        f32x4 s[4];
        __builtin_amdgcn_s_setprio(1);
#pragma unroll
        for (int nf = 0; nf < 4; ++nf) {
            const bf16x8 kf0 = *(const bf16x8*)(K + offK[nf][0]);
            const bf16x8 kf1 = *(const bf16x8*)(K + offK[nf][1]);
            f32x4 a = zf;
            a = __builtin_amdgcn_mfma_f32_16x16x32_bf16(kf0, aq0, a, 0, 0, 0);
            a = __builtin_amdgcn_mfma_f32_16x16x32_bf16(kf1, aq1, a, 0, 0, 0);
            s[nf] = a;
        }
        __builtin_amdgcn_s_setprio(0);

        // row max over 16 lane-local values + 2 shfl across the 4 dup lanes
        float mx = fmaxf(fmaxf(s[0][0], s[0][1]), s[0][2]);
        mx = fmaxf(fmaxf(mx, s[0][3]), s[1][0]);
        mx = fmaxf(fmaxf(mx, s[1][1]), s[1][2]);
        mx = fmaxf(fmaxf(mx, s[1][3]), s[2][0]);
        mx = fmaxf(fmaxf(mx, s[2][1]), s[2][2]);
        mx = fmaxf(fmaxf(mx, s[2][3]), s[3][0]);
        mx = fmaxf(fmaxf(mx, s[3][1]), s[3][2]);
        mx = fmaxf(mx, s[3][3]);
        mx = fmaxf(mx, __shfl_xor(mx, 16));
        mx = fmaxf(mx, __shfl_xor(mx, 32));
        mx *= QSCALE;

        // defer-max: rescale only when the row max grew by > 8 (log2 domain)
        if (!__all(mx <= m_run + 8.0f)) {
            const float mn = fmaxf(m_run, mx);
            const float alpha = exp2f(m_run - mn);
            m_run = mn;
            const float a0 = __shfl(alpha, l4 * 4 + 0);
            const float a1 = __shfl(alpha, l4 * 4 + 1);
            const float a2 = __shfl(alpha, l4 * 4 + 2);
            const float a3 = __shfl(alpha, l4 * 4 + 3);
#pragma unroll
            for (int df = 0; df < 4; ++df) {
                o[df][0] *= a0; o[df][1] *= a1; o[df][2] *= a2; o[df][3] *= a3;
            }
            accl[0] *= a0; accl[1] *= a1; accl[2] *= a2; accl[3] *= a3;
        }

        // P = exp2(QSCALE*s_raw - m), packed to per-wave LDS (b64 writes)
#pragma unroll
        for (int nf = 0; nf < 4; ++nf) {
            const float p0 = exp2f(fmaf(s[nf][0], QSCALE, -m_run));
            const float p1 = exp2f(fmaf(s[nf][1], QSCALE, -m_run));
            const float p2 = exp2f(fmaf(s[nf][2], QSCALE, -m_run));
            const float p3 = exp2f(fmaf(s[nf][3], QSCALE, -m_run));
            union { unsigned int d[2]; uint64_t q; } u;
            u.d[0] = cvt_pk_bf16(p0, p1);
            u.d[1] = cvt_pk_bf16(p2, p3);
            *(uint64_t*)(Pw + offPw[nf]) = u.q;
        }

        // O += P V ; rowsum via ones-column on the MFMA pipe
        const bf16x8 ap0 = *(const bf16x8*)(Pw + l15 * 64 + ((l4 ^ (l15 & 7)) << 3));
        const bf16x8 ap1 = *(const bf16x8*)(Pw + l15 * 64 + (((4 + l4) ^ (l15 & 7)) << 3));
        __builtin_amdgcn_s_setprio(1);
        accl = __builtin_amdgcn_mfma_f32_16x16x32_bf16(ap0, ones8, accl, 0, 0, 0);
        accl = __builtin_amdgcn_mfma_f32_16x16x32_bf16(ap1, ones8, accl, 0, 0, 0);
#pragma unroll
        for (int df = 0; df < 4; ++df) {
            const int r = df * 16 + l15;
            const bf16x8 bv0 = *(const bf16x8*)(V + r * 64 + ((l4 ^ (r & 7)) << 3));
            const bf16x8 bv1 = *(const bf16x8*)(V + r * 64 + (((4 + l4) ^ (r & 7)) << 3));
            o[df] = __builtin_amdgcn_mfma_f32_16x16x32_bf16(ap0, bv0, o[df], 0, 0, 0);
            o[df] = __builtin_amdgcn_mfma_f32_16x16x32_bf16(ap1, bv1, o[df], 0, 0, 0);
        }
        __builtin_amdgcn_s_setprio(0);

        if (more) {
#pragma unroll
            for (int p = 0; p < 2; ++p) {
                *(bf16x8*)(&lK[cur ^ 1][0] + p * 32 * 64 + swoff) = rk[p];
                *(bf16x8*)(&lV[cur ^ 1][0] + p * 32 * 64 + swoff) = rv[p];
            }
        }
        __syncthreads();
    }

    // epilogue: O / l  (accl rows aligned with o rows -> no shuffles)
    const float r0 = 1.0f / accl[0];
    const float r1 = 1.0f / accl[1];
    const float r2 = 1.0f / accl[2];
    const float r3 = 1.0f / accl[3];
    const int rowb = b * 2048 + qb + w * 16 + l4 * 4;
#pragma unroll
    for (int df = 0; df < 4; ++df) {
        const int d = df * 16 + l15;
        attn_out[(size_t)(rowb + 0) * 1024 + h * 64 + d] = f2bf(o[df][0] * r0);
        attn_out[(size_t)(rowb + 1) * 1024 + h * 64 + d] = f2bf(o[df][1] * r1);
        attn_out[(size_t)(rowb + 2) * 1024 + h * 64 + d] = f2bf(o[df][2] * r2);
        attn_out[(size_t)(rowb + 3) * 1024 + h * 64 + d] = f2bf(o[df][3] * r3);
    }
}

// ---------------------------------------------------------------------------
extern "C" void kernel_launch(void* const* d_in, const int* in_sizes, int n_in,
                              void* d_out, int out_size, void* d_ws, size_t ws_size,
                              hipStream_t stream) {
    const float* x      = (const float*)d_in[0];
    const float* w_qkv  = (const float*)d_in[1];
    const float* w_proj = (const float*)d_in[2];
    const float* b_proj = (const float*)d_in[3];
    float* out = (float*)d_out;

    char* ws = (char*)d_ws;
    unsigned short* xb     = (unsigned short*)(ws + 0);           //  8M
    unsigned short* wqkvT  = (unsigned short*)(ws + 8388608);     //  6M
    unsigned short* wprojT = (unsigned short*)(ws + 14680064);    //  2M
    unsigned short* qkv    = (unsigned short*)(ws + 16777216);    // 24M
    unsigned short* vt     = (unsigned short*)(ws + 41943040);    //  8M
    unsigned short* attn   = (unsigned short*)(ws + 50331648);    //  8M

    k_cvt_x<<<dim3(4096), dim3(256), 0, stream>>>(x, xb, 4096 * 1024 / 4);
    k_cvt_tr_w<<<dim3(48, 16), dim3(256), 0, stream>>>(w_qkv, wqkvT, 1024, 3072);
    k_cvt_tr_w<<<dim3(16, 16), dim3(256), 0, stream>>>(w_proj, wprojT, 1024, 1024);
    k_gemm_bt<1, 128><<<dim3(24, 32), dim3(256), 0, stream>>>(xb, wqkvT, (void*)qkv, (const float*)nullptr, vt, 4096, 3072, 1024);
    k_attn<<<dim3(32, 32), dim3(256), 0, stream>>>(qkv, vt, attn);
    k_gemm_bt<0, 64><<<dim3(16, 32), dim3(256), 0, stream>>>(attn, wprojT, (void*)out, b_proj, (unsigned short*)nullptr, 4096, 1024, 1024);
}